// Round 7
// baseline (410.065 us; speedup 1.0000x reference)
//
#include <hip/hip_runtime.h>
#include <hip/hip_bf16.h>
#include <stdint.h>

#define N_NODES 50000
#define N_EDGES 800000
#define HDIM 64
#define SCAN_N (N_NODES + 1)

// ---- workspace layout (CSR path) ----
#define MSG_BYTES  ((size_t)N_EDGES * HDIM * 2)      // 102,400,000 bf16 messages
#define INT_OFF    MSG_BYTES
#define DEG_OFF    (INT_OFF)
#define OFFS_OFF   (INT_OFF + 204800)
#define POS_OFF    (INT_OFF + 409600)
#define FB_OFF     (INT_OFF + 614400)
#define WS_NEED    (FB_OFF + (size_t)N_NODES * HDIM * 2)   // ~109.4 MB

typedef __attribute__((ext_vector_type(8))) short short8;
typedef __attribute__((ext_vector_type(4))) float floatx4;

__device__ __forceinline__ float bf2f(unsigned short u) {
    union { unsigned int i; float f; } v; v.i = ((unsigned int)u) << 16; return v.f;
}
__device__ __forceinline__ unsigned short f2bf(float f) {
    __hip_bfloat16 h = __float2bfloat16(f);
    return *reinterpret_cast<unsigned short*>(&h);
}

// Detect whether a float tensor was stored as bf16 (1) or f32 (0).
__device__ __forceinline__ int detect_is_bf16(const unsigned short* p) {
    int cnt = 0;
    #pragma unroll
    for (int i = 0; i < 64; ++i) {
        unsigned short b = p[i];
        int e = (b >> 7) & 0xFF;
        cnt += ((e >= 97 && e <= 157) || (b & 0x7FFF) == 0) ? 1 : 0;
    }
    return cnt >= 56;
}

__device__ __forceinline__ float getf(const void* p, unsigned int i, int isb) {
    return isb ? bf2f(((const unsigned short*)p)[i]) : ((const float*)p)[i];
}

__device__ __forceinline__ short8 get8bf(const void* p, unsigned int i, int isb) {
    if (isb) {
        return *reinterpret_cast<const short8*>((const short*)p + i);
    } else {
        const float4 f0 = *reinterpret_cast<const float4*>((const float*)p + i);
        const float4 f1 = *reinterpret_cast<const float4*>((const float*)p + i + 4);
        short8 a;
        a[0] = (short)f2bf(f0.x); a[1] = (short)f2bf(f0.y);
        a[2] = (short)f2bf(f0.z); a[3] = (short)f2bf(f0.w);
        a[4] = (short)f2bf(f1.x); a[5] = (short)f2bf(f1.y);
        a[6] = (short)f2bf(f1.z); a[7] = (short)f2bf(f1.w);
        return a;
    }
}

#define COMPILER_FENCE() asm volatile("" ::: "memory")
#define WAIT_LDS() __builtin_amdgcn_s_waitcnt(0xC07F)   // lgkmcnt(0) only

// ---------------------------------------------------------------------------
// feat -> contiguous bf16 table (one-time; removes per-gather f32 cvts and
// halves gather bytes in the edge kernel).
// ---------------------------------------------------------------------------
__global__ __launch_bounds__(256) void cvt_kernel(const void* __restrict__ feat,
                                                  unsigned short* __restrict__ fb) {
    const int isb = detect_is_bf16((const unsigned short*)feat);
    int i = (blockIdx.x * 256 + threadIdx.x) * 8;
    if (i >= N_NODES * HDIM) return;
    if (isb) {
        *reinterpret_cast<uint4*>(fb + i) =
            *reinterpret_cast<const uint4*>((const unsigned short*)feat + i);
    } else {
        float4 f0 = *reinterpret_cast<const float4*>((const float*)feat + i);
        float4 f1 = *reinterpret_cast<const float4*>((const float*)feat + i + 4);
        ushort4 a = {f2bf(f0.x), f2bf(f0.y), f2bf(f0.z), f2bf(f0.w)};
        ushort4 b = {f2bf(f1.x), f2bf(f1.y), f2bf(f1.z), f2bf(f1.w)};
        *reinterpret_cast<ushort4*>(fb + i)     = a;
        *reinterpret_cast<ushort4*>(fb + i + 4) = b;
    }
}

// ---------------------------------------------------------------------------
// CSR build: histogram + single-block fused exclusive scan
// ---------------------------------------------------------------------------
__global__ void hist_kernel(const int* __restrict__ dst, int* __restrict__ deg) {
    for (int e = blockIdx.x * blockDim.x + threadIdx.x; e < N_EDGES;
         e += gridDim.x * blockDim.x)
        atomicAdd(&deg[dst[e]], 1);
}

__global__ __launch_bounds__(1024) void scan_kernel(const int* __restrict__ deg,
                                                    int* __restrict__ offs,
                                                    int* __restrict__ pos) {
    __shared__ int s[1024];
    const int tid = threadIdx.x;
    const int CH = 49;                       // 1024*49 = 50176 >= 50001
    const int base = tid * CH;
    int sum = 0;
    for (int k = 0; k < CH; ++k) {
        int g = base + k;
        sum += (g < SCAN_N) ? deg[g] : 0;
    }
    s[tid] = sum;
    __syncthreads();
    for (int off = 1; off < 1024; off <<= 1) {   // Hillis-Steele inclusive
        int t = (tid >= off) ? s[tid - off] : 0;
        __syncthreads();
        s[tid] += t;
        __syncthreads();
    }
    int run = (tid > 0) ? s[tid - 1] : 0;        // exclusive chunk base
    for (int k = 0; k < CH; ++k) {
        int g = base + k;
        if (g < SCAN_N) {
            int d = deg[g];
            offs[g] = run; pos[g] = run;
            run += d;
        }
    }
}

// ---------------------------------------------------------------------------
// Edge kernel (templated): per wave, a 16-edge MFMA M-tile.
// CSR=true : A-gathers from the pre-converted bf16 table (4x16B/lane/iter);
//            claim slot with one int atomic/edge; 128B bf16 msg row stores.
// CSR=false: round-5 fallback, f32 atomics into msum, gathers original feat.
// ---------------------------------------------------------------------------
template <bool CSR>
__global__ __launch_bounds__(256, 2) void edge_kernel(
    const unsigned short* __restrict__ fbf,  // bf16 feat table (CSR path)
    const void* __restrict__ feat,           // original (detect + fallback)
    const void* __restrict__ xpos,
    const int* __restrict__ src, const int* __restrict__ dst,
    const void* __restrict__ W1, const void* __restrict__ b1,
    const void* __restrict__ W2, const void* __restrict__ b2,
    const void* __restrict__ we, const void* __restrict__ be,
    float* __restrict__ msum, unsigned int msum_cap,
    unsigned short* __restrict__ msg, int* __restrict__ pos)
{
    __shared__ __align__(16) short sA2[4][16][72];

    const int isb  = detect_is_bf16((const unsigned short*)feat);
    const int tid  = threadIdx.x;
    const int wave = tid >> 6;
    const int lane = tid & 63;
    const int l15  = lane & 15;
    const int quad = lane >> 4;

    short8 bw1[4][4];
    #pragma unroll
    for (int c = 0; c < 4; ++c)
        #pragma unroll
        for (int nt = 0; nt < 4; ++nt) {
            short8 b;
            #pragma unroll
            for (int j = 0; j < 8; ++j)
                b[j] = (short)f2bf(getf(W1, (c * 32 + quad * 8 + j) * 64 + nt * 16 + l15, isb));
            bw1[c][nt] = b;
        }
    short8 bw2[2][4];
    #pragma unroll
    for (int c = 0; c < 2; ++c)
        #pragma unroll
        for (int nt = 0; nt < 4; ++nt) {
            short8 b;
            #pragma unroll
            for (int j = 0; j < 8; ++j)
                b[j] = (short)f2bf(getf(W2, (c * 32 + quad * 8 + j) * 64 + nt * 16 + l15, isb));
            bw2[c][nt] = b;
        }
    float b1r[4], w1lr[4], b2r[4], wer[4];
    #pragma unroll
    for (int nt = 0; nt < 4; ++nt) {
        int n = nt * 16 + l15;
        b1r[nt]  = getf(b1, n, isb);
        w1lr[nt] = getf(W1, 128 * 64 + n, isb);
        b2r[nt]  = getf(b2, n, isb);
        wer[nt]  = getf(we, n, isb);
    }
    const float ber = getf(be, 0, isb);
    const int rowb = quad * 4;

    const int ntiles = N_EDGES / 64;
    for (int t = blockIdx.x; t < ntiles; t += gridDim.x) {
        const int ebase = t * 64 + wave * 16;

        int sidx = 0, didx = 0, slotv = 0;
        float sqd = 0.f;
        if (lane < 16) {
            int e = ebase + lane;
            sidx = src[e];
            didx = dst[e];
            if (CSR) slotv = atomicAdd(&pos[didx], 1);
            float dx = getf(xpos, sidx * 3 + 0, isb) - getf(xpos, didx * 3 + 0, isb);
            float dy = getf(xpos, sidx * 3 + 1, isb) - getf(xpos, didx * 3 + 1, isb);
            float dz = getf(xpos, sidx * 3 + 2, isb) - getf(xpos, didx * 3 + 2, isb);
            sqd = dx * dx + dy * dy + dz * dz;
        }
        const int sn     = __shfl(sidx, l15);
        const int dn_row = __shfl(didx, l15);

        // ---- layer 1: [16x128] @ [128x64] ----
        floatx4 acc[4];
        #pragma unroll
        for (int nt = 0; nt < 4; ++nt) acc[nt] = (floatx4){0.f, 0.f, 0.f, 0.f};
        #pragma unroll
        for (int c = 0; c < 4; ++c) {
            const int node = (c < 2) ? sn : dn_row;
            const unsigned int aoff = (unsigned int)node * 64u + (c & 1) * 32 + quad * 8;
            short8 a;
            if (CSR) a = *reinterpret_cast<const short8*>((const short*)fbf + aoff);
            else     a = get8bf(feat, aoff, isb);
            #pragma unroll
            for (int nt = 0; nt < 4; ++nt)
                acc[nt] = __builtin_amdgcn_mfma_f32_16x16x32_bf16(a, bw1[c][nt], acc[nt], 0, 0, 0);
        }

        // ---- epilogue 1 -> LDS ----
        float sq[4];
        #pragma unroll
        for (int r = 0; r < 4; ++r) sq[r] = __shfl(sqd, rowb + r);
        #pragma unroll
        for (int nt = 0; nt < 4; ++nt)
            #pragma unroll
            for (int r = 0; r < 4; ++r) {
                float v = fmaxf(acc[nt][r] + b1r[nt] + sq[r] * w1lr[nt], 0.f);
                sA2[wave][rowb + r][nt * 16 + l15] = (short)f2bf(v);
            }
        COMPILER_FENCE();
        WAIT_LDS();

        // ---- layer 2: [16x64] @ [64x64] ----
        floatx4 acc2[4];
        #pragma unroll
        for (int nt = 0; nt < 4; ++nt) acc2[nt] = (floatx4){0.f, 0.f, 0.f, 0.f};
        #pragma unroll
        for (int c = 0; c < 2; ++c) {
            short8 a = *reinterpret_cast<const short8*>(&sA2[wave][l15][c * 32 + quad * 8]);
            #pragma unroll
            for (int nt = 0; nt < 4; ++nt)
                acc2[nt] = __builtin_amdgcn_mfma_f32_16x16x32_bf16(a, bw2[c][nt], acc2[nt], 0, 0, 0);
        }
        COMPILER_FENCE();

        // ---- epilogue 2: relu, gate ----
        float mval[4][4];
        float part[4] = {0.f, 0.f, 0.f, 0.f};
        #pragma unroll
        for (int nt = 0; nt < 4; ++nt)
            #pragma unroll
            for (int r = 0; r < 4; ++r) {
                float v = fmaxf(acc2[nt][r] + b2r[nt], 0.f);
                mval[nt][r] = v;
                part[r] += v * wer[nt];
            }
        #pragma unroll
        for (int off = 1; off < 16; off <<= 1)
            #pragma unroll
            for (int r = 0; r < 4; ++r) part[r] += __shfl_xor(part[r], off);
        float gate[4];
        #pragma unroll
        for (int r = 0; r < 4; ++r)
            gate[r] = 1.f / (1.f + __expf(-(part[r] + ber)));

        if (CSR) {
            #pragma unroll
            for (int nt = 0; nt < 4; ++nt)
                #pragma unroll
                for (int r = 0; r < 4; ++r)
                    sA2[wave][rowb + r][nt * 16 + l15] = (short)f2bf(mval[nt][r] * gate[r]);
            COMPILER_FENCE();
            WAIT_LDS();
            int slot_r = __shfl(slotv, l15);
            const short8 v0 = *reinterpret_cast<const short8*>(&sA2[wave][l15][quad * 16]);
            const short8 v1 = *reinterpret_cast<const short8*>(&sA2[wave][l15][quad * 16 + 8]);
            unsigned short* mp = msg + (size_t)slot_r * 64 + quad * 16;
            *reinterpret_cast<short8*>(mp)     = v0;
            *reinterpret_cast<short8*>(mp + 8) = v1;
            COMPILER_FENCE();
        } else {
            #pragma unroll
            for (int r = 0; r < 4; ++r) {
                int dn = __shfl(didx, rowb + r);
                unsigned int base = (unsigned int)dn * 64u;
                if (base + 64u <= msum_cap) {
                    #pragma unroll
                    for (int nt = 0; nt < 4; ++nt)
                        unsafeAtomicAdd(&msum[base + nt * 16 + l15], mval[nt][r] * gate[r]);
                }
            }
        }
    }
}

// ---------------------------------------------------------------------------
// Node kernel (templated): per wave a 16-node MFMA M-tile.
// MSGRED=true : fused reduction — each lane sums its node's contiguous bf16
//               msg rows straight into the h-fragment (no msum round-trip).
// MSGRED=false: fallback, reads pre-accumulated f32 msum.
// ---------------------------------------------------------------------------
template <bool MSGRED>
__global__ __launch_bounds__(256, 2) void node_kernel(
    const unsigned short* __restrict__ msg, const int* __restrict__ offs,
    const float* __restrict__ msum,
    const void* __restrict__ feat,
    const void* __restrict__ U1, const void* __restrict__ c1v,
    const void* __restrict__ U2, const void* __restrict__ c2v,
    void* __restrict__ out)
{
    __shared__ __align__(16) short sT[4][16][72];

    const int isb  = detect_is_bf16((const unsigned short*)feat);
    const int tid  = threadIdx.x;
    const int wave = tid >> 6;
    const int lane = tid & 63;
    const int l15  = lane & 15;
    const int quad = lane >> 4;

    short8 u1f[2][4], u2f[2][4];
    #pragma unroll
    for (int c = 0; c < 2; ++c)
        #pragma unroll
        for (int nt = 0; nt < 4; ++nt) {
            short8 a, b;
            #pragma unroll
            for (int j = 0; j < 8; ++j) {
                int k = c * 32 + quad * 8 + j, n = nt * 16 + l15;
                a[j] = (short)f2bf(getf(U1, k * 64 + n, isb));
                b[j] = (short)f2bf(getf(U2, k * 64 + n, isb));
            }
            u1f[c][nt] = a; u2f[c][nt] = b;
        }
    float c1r[4], c2r[4];
    #pragma unroll
    for (int nt = 0; nt < 4; ++nt) {
        c1r[nt] = getf(c1v, nt * 16 + l15, isb);
        c2r[nt] = getf(c2v, nt * 16 + l15, isb);
    }
    const int rowb = quad * 4;

    const int ntile = (N_NODES + 15) / 16;   // 3125
    const int t = blockIdx.x * 4 + wave;
    if (t < ntile) {
        const int node = t * 16 + l15;

        // ---- message sum for this lane's 16 columns (c*32+quad*8+j) ----
        float acc16[16];
        #pragma unroll
        for (int i = 0; i < 16; ++i) acc16[i] = 0.f;
        if (MSGRED) {
            int s = offs[node], e = offs[node + 1];
            for (int j = s; j < e; ++j) {
                const unsigned short* p = msg + (size_t)j * 64 + quad * 8;
                short8 a0 = *reinterpret_cast<const short8*>(p);        // cols quad*8..+8
                short8 a1 = *reinterpret_cast<const short8*>(p + 32);   // cols 32+quad*8..+8
                #pragma unroll
                for (int i = 0; i < 8; ++i) {
                    acc16[i]     += bf2f((unsigned short)a0[i]);
                    acc16[8 + i] += bf2f((unsigned short)a1[i]);
                }
            }
        } else {
            #pragma unroll
            for (int c = 0; c < 2; ++c) {
                unsigned int off = (unsigned int)node * 64u + c * 32 + quad * 8;
                float4 m0 = *reinterpret_cast<const float4*>(msum + off);
                float4 m1 = *reinterpret_cast<const float4*>(msum + off + 4);
                acc16[c * 8 + 0] = m0.x; acc16[c * 8 + 1] = m0.y;
                acc16[c * 8 + 2] = m0.z; acc16[c * 8 + 3] = m0.w;
                acc16[c * 8 + 4] = m1.x; acc16[c * 8 + 5] = m1.y;
                acc16[c * 8 + 6] = m1.z; acc16[c * 8 + 7] = m1.w;
            }
        }

        // ---- h fragments ----
        short8 ah[2];
        #pragma unroll
        for (int c = 0; c < 2; ++c) {
            unsigned int off = (unsigned int)node * 64u + c * 32 + quad * 8;
            short8 a;
            #pragma unroll
            for (int j = 0; j < 8; ++j)
                a[j] = (short)f2bf(acc16[c * 8 + j] + getf(feat, off + j, isb));
            ah[c] = a;
        }

        // ---- layer 1: relu(h@U1+c1) ----
        floatx4 acc[4];
        #pragma unroll
        for (int nt = 0; nt < 4; ++nt) acc[nt] = (floatx4){0.f, 0.f, 0.f, 0.f};
        #pragma unroll
        for (int c = 0; c < 2; ++c)
            #pragma unroll
            for (int nt = 0; nt < 4; ++nt)
                acc[nt] = __builtin_amdgcn_mfma_f32_16x16x32_bf16(ah[c], u1f[c][nt], acc[nt], 0, 0, 0);

        #pragma unroll
        for (int nt = 0; nt < 4; ++nt)
            #pragma unroll
            for (int r = 0; r < 4; ++r) {
                float v = fmaxf(acc[nt][r] + c1r[nt], 0.f);
                sT[wave][rowb + r][nt * 16 + l15] = (short)f2bf(v);
            }
        COMPILER_FENCE();
        WAIT_LDS();

        // ---- layer 2: t@U2 + c2 + feat ----
        floatx4 acc2[4];
        #pragma unroll
        for (int nt = 0; nt < 4; ++nt) acc2[nt] = (floatx4){0.f, 0.f, 0.f, 0.f};
        #pragma unroll
        for (int c = 0; c < 2; ++c) {
            short8 a = *reinterpret_cast<const short8*>(&sT[wave][l15][c * 32 + quad * 8]);
            #pragma unroll
            for (int nt = 0; nt < 4; ++nt)
                acc2[nt] = __builtin_amdgcn_mfma_f32_16x16x32_bf16(a, u2f[c][nt], acc2[nt], 0, 0, 0);
        }
        COMPILER_FENCE();

        #pragma unroll
        for (int r = 0; r < 4; ++r) {
            unsigned int row = (unsigned int)(t * 16 + rowb + r);
            #pragma unroll
            for (int nt = 0; nt < 4; ++nt) {
                unsigned int off = row * 64u + nt * 16 + l15;
                float v = acc2[nt][r] + c2r[nt] + getf(feat, off, isb);
                if (isb) ((unsigned short*)out)[off] = f2bf(v);
                else     ((float*)out)[off] = v;
            }
        }
    }
}

extern "C" void kernel_launch(void* const* d_in, const int* in_sizes, int n_in,
                              void* d_out, int out_size, void* d_ws, size_t ws_size,
                              hipStream_t stream) {
    const void* feat = d_in[0];
    const void* x    = d_in[1];
    const int* src   = (const int*)d_in[2];
    const int* dst   = (const int*)d_in[3];
    const void* W1   = d_in[4];
    const void* b1   = d_in[5];
    const void* W2   = d_in[6];
    const void* b2   = d_in[7];
    const void* we   = d_in[8];
    const void* be   = d_in[9];
    const void* U1   = d_in[10];
    const void* c1   = d_in[11];
    const void* U2   = d_in[12];
    const void* c2   = d_in[13];
    char* ws = (char*)d_ws;

    if (ws_size >= WS_NEED) {
        // ---------------- CSR scatter->gather path ----------------
        unsigned short* msg = (unsigned short*)(ws);
        int* deg  = (int*)(ws + DEG_OFF);
        int* offs = (int*)(ws + OFFS_OFF);
        int* pos  = (int*)(ws + POS_OFF);
        unsigned short* fb = (unsigned short*)(ws + FB_OFF);

        hipMemsetAsync(deg, 0, 204800, stream);
        cvt_kernel<<<(N_NODES * HDIM / 8 + 255) / 256, 256, 0, stream>>>(feat, fb);
        hist_kernel<<<1024, 256, 0, stream>>>(dst, deg);
        scan_kernel<<<1, 1024, 0, stream>>>(deg, offs, pos);
        edge_kernel<true><<<2500, 256, 0, stream>>>(fb, feat, x, src, dst, W1, b1, W2, b2,
                                                    we, be, nullptr, 0xFFFFFFFFu, msg, pos);
        node_kernel<true><<<((N_NODES + 15) / 16 + 3) / 4, 256, 0, stream>>>(
            msg, offs, nullptr, feat, U1, c1, U2, c2, d_out);
    } else {
        // ---------------- fallback: round-5 atomic path ----------------
        float* msum = (float*)ws;
        size_t need = (size_t)N_NODES * HDIM * sizeof(float);
        size_t clr  = need < ws_size ? need : ws_size;
        unsigned int cap = (unsigned int)(ws_size / sizeof(float));
        if (cap > (unsigned int)(N_NODES * HDIM)) cap = (unsigned int)(N_NODES * HDIM);

        hipMemsetAsync(msum, 0, clr, stream);
        edge_kernel<false><<<2500, 256, 0, stream>>>(nullptr, feat, x, src, dst, W1, b1, W2, b2,
                                                     we, be, msum, cap, nullptr, nullptr);
        node_kernel<false><<<((N_NODES + 15) / 16 + 3) / 4, 256, 0, stream>>>(
            nullptr, nullptr, msum, feat, U1, c1, U2, c2, d_out);
    }
}

// Round 8
// 278.050 us; speedup vs baseline: 1.4748x; 1.4748x over previous
//
#include <hip/hip_runtime.h>
#include <hip/hip_bf16.h>
#include <stdint.h>

#define N_NODES 50000
#define N_EDGES 800000
#define HDIM 64
#define SCAN_N (N_NODES + 1)

// ---- workspace layout (CSR path) ----
#define MSG_BYTES  ((size_t)N_EDGES * HDIM * 2)      // 102,400,000 bf16 messages
#define INT_OFF    MSG_BYTES
#define DEG_OFF    (INT_OFF)
#define OFFS_OFF   (INT_OFF + 204800)
#define POS_OFF    (INT_OFF + 409600)
#define FB_OFF     (INT_OFF + 614400)
#define W1T_OFF    (FB_OFF + (size_t)N_NODES * HDIM * 2)
#define W2T_OFF    (W1T_OFF + 16384)
#define U1T_OFF    (W2T_OFF + 8192)
#define U2T_OFF    (U1T_OFF + 8192)
#define WS_NEED    (U2T_OFF + 8192)     // ~109.5 MB (r6 ran with 115.8 MB need)

typedef __attribute__((ext_vector_type(8))) short short8;
typedef __attribute__((ext_vector_type(4))) float floatx4;

__device__ __forceinline__ float bf2f(unsigned short u) {
    union { unsigned int i; float f; } v; v.i = ((unsigned int)u) << 16; return v.f;
}
__device__ __forceinline__ unsigned short f2bf(float f) {
    __hip_bfloat16 h = __float2bfloat16(f);
    return *reinterpret_cast<unsigned short*>(&h);
}

__device__ __forceinline__ int detect_is_bf16(const unsigned short* p) {
    int cnt = 0;
    #pragma unroll
    for (int i = 0; i < 64; ++i) {
        unsigned short b = p[i];
        int e = (b >> 7) & 0xFF;
        cnt += ((e >= 97 && e <= 157) || (b & 0x7FFF) == 0) ? 1 : 0;
    }
    return cnt >= 56;
}

__device__ __forceinline__ float getf(const void* p, unsigned int i, int isb) {
    return isb ? bf2f(((const unsigned short*)p)[i]) : ((const float*)p)[i];
}

__device__ __forceinline__ short8 get8bf(const void* p, unsigned int i, int isb) {
    if (isb) {
        return *reinterpret_cast<const short8*>((const short*)p + i);
    } else {
        const float4 f0 = *reinterpret_cast<const float4*>((const float*)p + i);
        const float4 f1 = *reinterpret_cast<const float4*>((const float*)p + i + 4);
        short8 a;
        a[0] = (short)f2bf(f0.x); a[1] = (short)f2bf(f0.y);
        a[2] = (short)f2bf(f0.z); a[3] = (short)f2bf(f0.w);
        a[4] = (short)f2bf(f1.x); a[5] = (short)f2bf(f1.y);
        a[6] = (short)f2bf(f1.z); a[7] = (short)f2bf(f1.w);
        return a;
    }
}

#define COMPILER_FENCE() asm volatile("" ::: "memory")
#define WAIT_LDS() __builtin_amdgcn_s_waitcnt(0xC07F)   // lgkmcnt(0) only

// ---------------------------------------------------------------------------
// feat -> contiguous bf16 table
// ---------------------------------------------------------------------------
__global__ __launch_bounds__(256) void cvt_kernel(const void* __restrict__ feat,
                                                  unsigned short* __restrict__ fb) {
    const int isb = detect_is_bf16((const unsigned short*)feat);
    int i = (blockIdx.x * 256 + threadIdx.x) * 8;
    if (i >= N_NODES * HDIM) return;
    if (isb) {
        *reinterpret_cast<uint4*>(fb + i) =
            *reinterpret_cast<const uint4*>((const unsigned short*)feat + i);
    } else {
        float4 f0 = *reinterpret_cast<const float4*>((const float*)feat + i);
        float4 f1 = *reinterpret_cast<const float4*>((const float*)feat + i + 4);
        ushort4 a = {f2bf(f0.x), f2bf(f0.y), f2bf(f0.z), f2bf(f0.w)};
        ushort4 b = {f2bf(f1.x), f2bf(f1.y), f2bf(f1.z), f2bf(f1.w)};
        *reinterpret_cast<ushort4*>(fb + i)     = a;
        *reinterpret_cast<ushort4*>(fb + i + 4) = b;
    }
}

// ---------------------------------------------------------------------------
// Transposed bf16 weight tables: XT[n][k] = X[k][n]; fragment loads become
// one 16B vector load instead of 8 scalar gathers.
// ---------------------------------------------------------------------------
__global__ __launch_bounds__(256) void prepw_kernel(
    const void* __restrict__ feat,      // for dtype detect
    const void* __restrict__ W1, const void* __restrict__ W2,
    const void* __restrict__ U1, const void* __restrict__ U2,
    unsigned short* __restrict__ w1t, unsigned short* __restrict__ w2t,
    unsigned short* __restrict__ u1t, unsigned short* __restrict__ u2t)
{
    const int isb = detect_is_bf16((const unsigned short*)feat);
    int idx = blockIdx.x * 256 + threadIdx.x;
    if (idx < 8192) {                               // W1T [64][128]
        int n = idx >> 7, k = idx & 127;
        w1t[idx] = f2bf(getf(W1, k * 64 + n, isb));
    } else if (idx < 12288) {                       // W2T [64][64]
        int i = idx - 8192, n = i >> 6, k = i & 63;
        w2t[i] = f2bf(getf(W2, k * 64 + n, isb));
    } else if (idx < 16384) {                       // U1T
        int i = idx - 12288, n = i >> 6, k = i & 63;
        u1t[i] = f2bf(getf(U1, k * 64 + n, isb));
    } else if (idx < 20480) {                       // U2T
        int i = idx - 16384, n = i >> 6, k = i & 63;
        u2t[i] = f2bf(getf(U2, k * 64 + n, isb));
    }
}

// ---------------------------------------------------------------------------
// CSR build: histogram + multi-block scan (r6-proven; r7's single-block scan
// serialized ~150k memory ops on one CU and cost ~80 us)
// ---------------------------------------------------------------------------
__global__ void hist_kernel(const int* __restrict__ dst, int* __restrict__ deg) {
    for (int e = blockIdx.x * blockDim.x + threadIdx.x; e < N_EDGES;
         e += gridDim.x * blockDim.x)
        atomicAdd(&deg[dst[e]], 1);
}

__global__ void scan1_kernel(const int* __restrict__ deg, int* __restrict__ part) {
    __shared__ int s[1024];
    int g = blockIdx.x * 1024 + threadIdx.x;
    s[threadIdx.x] = (g < SCAN_N) ? deg[g] : 0;
    __syncthreads();
    for (int off = 512; off > 0; off >>= 1) {
        if (threadIdx.x < off) s[threadIdx.x] += s[threadIdx.x + off];
        __syncthreads();
    }
    if (threadIdx.x == 0) part[blockIdx.x] = s[0];
}

__global__ void scan2_kernel(int* __restrict__ part, int nparts) {
    if (threadIdx.x == 0) {
        int run = 0;
        for (int i = 0; i < nparts; ++i) { int t = part[i]; part[i] = run; run += t; }
    }
}

__global__ void scan3_kernel(const int* __restrict__ deg, const int* __restrict__ part,
                             int* __restrict__ offs, int* __restrict__ pos) {
    __shared__ int s[1024];
    int g = blockIdx.x * 1024 + threadIdx.x;
    int v = (g < SCAN_N) ? deg[g] : 0;
    s[threadIdx.x] = v;
    __syncthreads();
    for (int off = 1; off < 1024; off <<= 1) {
        int t = (threadIdx.x >= off) ? s[threadIdx.x - off] : 0;
        __syncthreads();
        s[threadIdx.x] += t;
        __syncthreads();
    }
    int excl = s[threadIdx.x] - v + part[blockIdx.x];
    if (g < SCAN_N) { offs[g] = excl; pos[g] = excl; }
}

// ---------------------------------------------------------------------------
// Edge kernel: per wave, a 16-edge MFMA M-tile.
// ---------------------------------------------------------------------------
template <bool CSR>
__global__ __launch_bounds__(256, 2) void edge_kernel(
    const unsigned short* __restrict__ fbf,
    const unsigned short* __restrict__ w1t, const unsigned short* __restrict__ w2t,
    const void* __restrict__ feat, const void* __restrict__ xpos,
    const int* __restrict__ src, const int* __restrict__ dst,
    const void* __restrict__ W1, const void* __restrict__ b1,
    const void* __restrict__ W2, const void* __restrict__ b2,
    const void* __restrict__ we, const void* __restrict__ be,
    float* __restrict__ msum, unsigned int msum_cap,
    unsigned short* __restrict__ msg, int* __restrict__ pos)
{
    __shared__ __align__(16) short sA2[4][16][72];

    const int isb  = detect_is_bf16((const unsigned short*)feat);
    const int tid  = threadIdx.x;
    const int wave = tid >> 6;
    const int lane = tid & 63;
    const int l15  = lane & 15;
    const int quad = lane >> 4;

    // ---- persistent B fragments ----
    short8 bw1[4][4];
    short8 bw2[2][4];
    if (CSR) {
        #pragma unroll
        for (int nt = 0; nt < 4; ++nt) {
            const int n = nt * 16 + l15;
            #pragma unroll
            for (int c = 0; c < 4; ++c)
                bw1[c][nt] = *reinterpret_cast<const short8*>(w1t + n * 128 + c * 32 + quad * 8);
            #pragma unroll
            for (int c = 0; c < 2; ++c)
                bw2[c][nt] = *reinterpret_cast<const short8*>(w2t + n * 64 + c * 32 + quad * 8);
        }
    } else {
        #pragma unroll
        for (int c = 0; c < 4; ++c)
            #pragma unroll
            for (int nt = 0; nt < 4; ++nt) {
                short8 b;
                #pragma unroll
                for (int j = 0; j < 8; ++j)
                    b[j] = (short)f2bf(getf(W1, (c * 32 + quad * 8 + j) * 64 + nt * 16 + l15, isb));
                bw1[c][nt] = b;
            }
        #pragma unroll
        for (int c = 0; c < 2; ++c)
            #pragma unroll
            for (int nt = 0; nt < 4; ++nt) {
                short8 b;
                #pragma unroll
                for (int j = 0; j < 8; ++j)
                    b[j] = (short)f2bf(getf(W2, (c * 32 + quad * 8 + j) * 64 + nt * 16 + l15, isb));
                bw2[c][nt] = b;
            }
    }
    float b1r[4], w1lr[4], b2r[4], wer[4];
    #pragma unroll
    for (int nt = 0; nt < 4; ++nt) {
        int n = nt * 16 + l15;
        b1r[nt]  = getf(b1, n, isb);
        w1lr[nt] = getf(W1, 128 * 64 + n, isb);
        b2r[nt]  = getf(b2, n, isb);
        wer[nt]  = getf(we, n, isb);
    }
    const float ber = getf(be, 0, isb);
    const int rowb = quad * 4;

    const int ntiles = N_EDGES / 64;
    for (int t = blockIdx.x; t < ntiles; t += gridDim.x) {
        const int ebase = t * 64 + wave * 16;

        int sidx = 0, didx = 0, slotv = 0;
        float sqd = 0.f;
        if (lane < 16) {
            int e = ebase + lane;
            sidx = src[e];
            didx = dst[e];
            if (CSR) slotv = atomicAdd(&pos[didx], 1);
            float dx = getf(xpos, sidx * 3 + 0, isb) - getf(xpos, didx * 3 + 0, isb);
            float dy = getf(xpos, sidx * 3 + 1, isb) - getf(xpos, didx * 3 + 1, isb);
            float dz = getf(xpos, sidx * 3 + 2, isb) - getf(xpos, didx * 3 + 2, isb);
            sqd = dx * dx + dy * dy + dz * dz;
        }
        const int sn     = __shfl(sidx, l15);
        const int dn_row = __shfl(didx, l15);

        // ---- layer 1: [16x128] @ [128x64] ----
        floatx4 acc[4];
        #pragma unroll
        for (int nt = 0; nt < 4; ++nt) acc[nt] = (floatx4){0.f, 0.f, 0.f, 0.f};
        #pragma unroll
        for (int c = 0; c < 4; ++c) {
            const int node = (c < 2) ? sn : dn_row;
            const unsigned int aoff = (unsigned int)node * 64u + (c & 1) * 32 + quad * 8;
            short8 a;
            if (CSR) a = *reinterpret_cast<const short8*>((const short*)fbf + aoff);
            else     a = get8bf(feat, aoff, isb);
            #pragma unroll
            for (int nt = 0; nt < 4; ++nt)
                acc[nt] = __builtin_amdgcn_mfma_f32_16x16x32_bf16(a, bw1[c][nt], acc[nt], 0, 0, 0);
        }

        // ---- epilogue 1 -> LDS ----
        float sq[4];
        #pragma unroll
        for (int r = 0; r < 4; ++r) sq[r] = __shfl(sqd, rowb + r);
        #pragma unroll
        for (int nt = 0; nt < 4; ++nt)
            #pragma unroll
            for (int r = 0; r < 4; ++r) {
                float v = fmaxf(acc[nt][r] + b1r[nt] + sq[r] * w1lr[nt], 0.f);
                sA2[wave][rowb + r][nt * 16 + l15] = (short)f2bf(v);
            }
        COMPILER_FENCE();
        WAIT_LDS();

        // ---- layer 2: [16x64] @ [64x64] ----
        floatx4 acc2[4];
        #pragma unroll
        for (int nt = 0; nt < 4; ++nt) acc2[nt] = (floatx4){0.f, 0.f, 0.f, 0.f};
        #pragma unroll
        for (int c = 0; c < 2; ++c) {
            short8 a = *reinterpret_cast<const short8*>(&sA2[wave][l15][c * 32 + quad * 8]);
            #pragma unroll
            for (int nt = 0; nt < 4; ++nt)
                acc2[nt] = __builtin_amdgcn_mfma_f32_16x16x32_bf16(a, bw2[c][nt], acc2[nt], 0, 0, 0);
        }
        COMPILER_FENCE();

        // ---- epilogue 2 ----
        float mval[4][4];
        float part[4] = {0.f, 0.f, 0.f, 0.f};
        #pragma unroll
        for (int nt = 0; nt < 4; ++nt)
            #pragma unroll
            for (int r = 0; r < 4; ++r) {
                float v = fmaxf(acc2[nt][r] + b2r[nt], 0.f);
                mval[nt][r] = v;
                part[r] += v * wer[nt];
            }
        #pragma unroll
        for (int off = 1; off < 16; off <<= 1)
            #pragma unroll
            for (int r = 0; r < 4; ++r) part[r] += __shfl_xor(part[r], off);
        float gate[4];
        #pragma unroll
        for (int r = 0; r < 4; ++r)
            gate[r] = 1.f / (1.f + __expf(-(part[r] + ber)));

        if (CSR) {
            #pragma unroll
            for (int nt = 0; nt < 4; ++nt)
                #pragma unroll
                for (int r = 0; r < 4; ++r)
                    sA2[wave][rowb + r][nt * 16 + l15] = (short)f2bf(mval[nt][r] * gate[r]);
            COMPILER_FENCE();
            WAIT_LDS();
            int slot_r = __shfl(slotv, l15);
            const short8 v0 = *reinterpret_cast<const short8*>(&sA2[wave][l15][quad * 16]);
            const short8 v1 = *reinterpret_cast<const short8*>(&sA2[wave][l15][quad * 16 + 8]);
            unsigned short* mp = msg + (size_t)slot_r * 64 + quad * 16;
            *reinterpret_cast<short8*>(mp)     = v0;
            *reinterpret_cast<short8*>(mp + 8) = v1;
            COMPILER_FENCE();
        } else {
            #pragma unroll
            for (int r = 0; r < 4; ++r) {
                int dn = __shfl(didx, rowb + r);
                unsigned int base = (unsigned int)dn * 64u;
                if (base + 64u <= msum_cap) {
                    #pragma unroll
                    for (int nt = 0; nt < 4; ++nt)
                        unsafeAtomicAdd(&msum[base + nt * 16 + l15], mval[nt][r] * gate[r]);
                }
            }
        }
    }
}

// ---------------------------------------------------------------------------
// Node kernel: per wave a 16-node MFMA M-tile, fused msg reduction (MSGRED),
// vectorized h-build, LDS-coalesced epilogue.
// ---------------------------------------------------------------------------
template <bool MSGRED>
__global__ __launch_bounds__(256, 2) void node_kernel(
    const unsigned short* __restrict__ msg, const int* __restrict__ offs,
    const float* __restrict__ msum,
    const unsigned short* __restrict__ u1t, const unsigned short* __restrict__ u2t,
    const void* __restrict__ feat,
    const void* __restrict__ U1, const void* __restrict__ c1v,
    const void* __restrict__ U2, const void* __restrict__ c2v,
    void* __restrict__ out)
{
    __shared__ __align__(16) short sT[4][16][72];
    __shared__ __align__(16) float sF[4][16][68];

    const int isb  = detect_is_bf16((const unsigned short*)feat);
    const int tid  = threadIdx.x;
    const int wave = tid >> 6;
    const int lane = tid & 63;
    const int l15  = lane & 15;
    const int quad = lane >> 4;

    short8 u1f[2][4], u2f[2][4];
    if (MSGRED) {
        #pragma unroll
        for (int nt = 0; nt < 4; ++nt) {
            const int n = nt * 16 + l15;
            #pragma unroll
            for (int c = 0; c < 2; ++c) {
                u1f[c][nt] = *reinterpret_cast<const short8*>(u1t + n * 64 + c * 32 + quad * 8);
                u2f[c][nt] = *reinterpret_cast<const short8*>(u2t + n * 64 + c * 32 + quad * 8);
            }
        }
    } else {
        #pragma unroll
        for (int c = 0; c < 2; ++c)
            #pragma unroll
            for (int nt = 0; nt < 4; ++nt) {
                short8 a, b;
                #pragma unroll
                for (int j = 0; j < 8; ++j) {
                    int k = c * 32 + quad * 8 + j, n = nt * 16 + l15;
                    a[j] = (short)f2bf(getf(U1, k * 64 + n, isb));
                    b[j] = (short)f2bf(getf(U2, k * 64 + n, isb));
                }
                u1f[c][nt] = a; u2f[c][nt] = b;
            }
    }
    float c1r[4], c2r[4];
    #pragma unroll
    for (int nt = 0; nt < 4; ++nt) {
        c1r[nt] = getf(c1v, nt * 16 + l15, isb);
        c2r[nt] = getf(c2v, nt * 16 + l15, isb);
    }
    const int rowb = quad * 4;

    const int ntile = (N_NODES + 15) / 16;   // 3125
    const int t = blockIdx.x * 4 + wave;
    if (t < ntile) {
        const int node = t * 16 + l15;       // this lane's A-row (and out-row)

        // ---- message sum for this lane's 16 columns ----
        float acc16[16];
        #pragma unroll
        for (int i = 0; i < 16; ++i) acc16[i] = 0.f;
        if (MSGRED) {
            int s = offs[node], e = offs[node + 1];
            for (int j = s; j < e; ++j) {
                const unsigned short* p = msg + (size_t)j * 64 + quad * 8;
                short8 a0 = *reinterpret_cast<const short8*>(p);
                short8 a1 = *reinterpret_cast<const short8*>(p + 32);
                #pragma unroll
                for (int i = 0; i < 8; ++i) {
                    acc16[i]     += bf2f((unsigned short)a0[i]);
                    acc16[8 + i] += bf2f((unsigned short)a1[i]);
                }
            }
        } else {
            #pragma unroll
            for (int c = 0; c < 2; ++c) {
                unsigned int off = (unsigned int)node * 64u + c * 32 + quad * 8;
                float4 m0 = *reinterpret_cast<const float4*>(msum + off);
                float4 m1 = *reinterpret_cast<const float4*>(msum + off + 4);
                acc16[c * 8 + 0] = m0.x; acc16[c * 8 + 1] = m0.y;
                acc16[c * 8 + 2] = m0.z; acc16[c * 8 + 3] = m0.w;
                acc16[c * 8 + 4] = m1.x; acc16[c * 8 + 5] = m1.y;
                acc16[c * 8 + 6] = m1.z; acc16[c * 8 + 7] = m1.w;
            }
        }

        // ---- h fragments (vectorized f32/bf16 feat loads, same math) ----
        short8 ah[2];
        #pragma unroll
        for (int c = 0; c < 2; ++c) {
            unsigned int off = (unsigned int)node * 64u + c * 32 + quad * 8;
            float hv[8];
            if (isb) {
                short8 fv = *reinterpret_cast<const short8*>((const short*)feat + off);
                #pragma unroll
                for (int j = 0; j < 8; ++j) hv[j] = bf2f((unsigned short)fv[j]);
            } else {
                float4 f0 = *reinterpret_cast<const float4*>((const float*)feat + off);
                float4 f1 = *reinterpret_cast<const float4*>((const float*)feat + off + 4);
                hv[0] = f0.x; hv[1] = f0.y; hv[2] = f0.z; hv[3] = f0.w;
                hv[4] = f1.x; hv[5] = f1.y; hv[6] = f1.z; hv[7] = f1.w;
            }
            short8 a;
            #pragma unroll
            for (int j = 0; j < 8; ++j) a[j] = (short)f2bf(acc16[c * 8 + j] + hv[j]);
            ah[c] = a;
        }

        // ---- layer 1: relu(h@U1+c1) ----
        floatx4 acc[4];
        #pragma unroll
        for (int nt = 0; nt < 4; ++nt) acc[nt] = (floatx4){0.f, 0.f, 0.f, 0.f};
        #pragma unroll
        for (int c = 0; c < 2; ++c)
            #pragma unroll
            for (int nt = 0; nt < 4; ++nt)
                acc[nt] = __builtin_amdgcn_mfma_f32_16x16x32_bf16(ah[c], u1f[c][nt], acc[nt], 0, 0, 0);

        #pragma unroll
        for (int nt = 0; nt < 4; ++nt)
            #pragma unroll
            for (int r = 0; r < 4; ++r) {
                float v = fmaxf(acc[nt][r] + c1r[nt], 0.f);
                sT[wave][rowb + r][nt * 16 + l15] = (short)f2bf(v);
            }
        COMPILER_FENCE();
        WAIT_LDS();

        // ---- layer 2 ----
        floatx4 acc2[4];
        #pragma unroll
        for (int nt = 0; nt < 4; ++nt) acc2[nt] = (floatx4){0.f, 0.f, 0.f, 0.f};
        #pragma unroll
        for (int c = 0; c < 2; ++c) {
            short8 a = *reinterpret_cast<const short8*>(&sT[wave][l15][c * 32 + quad * 8]);
            #pragma unroll
            for (int nt = 0; nt < 4; ++nt)
                acc2[nt] = __builtin_amdgcn_mfma_f32_16x16x32_bf16(a, u2f[c][nt], acc2[nt], 0, 0, 0);
        }
        COMPILER_FENCE();

        // ---- epilogue: D-layout -> f32 LDS -> row-coalesced (+feat) store ----
        #pragma unroll
        for (int nt = 0; nt < 4; ++nt)
            #pragma unroll
            for (int r = 0; r < 4; ++r)
                sF[wave][rowb + r][nt * 16 + l15] = acc2[nt][r] + c2r[nt];
        COMPILER_FENCE();
        WAIT_LDS();

        const unsigned int ob = (unsigned int)node * 64u + quad * 16;
        if (isb) {
            const unsigned short* fp = (const unsigned short*)feat + ob;
            unsigned short* op = (unsigned short*)out + ob;
            #pragma unroll
            for (int k = 0; k < 2; ++k) {
                ushort4 o0, o1;
                float4 v0 = *reinterpret_cast<const float4*>(&sF[wave][l15][quad * 16 + k * 8]);
                float4 v1 = *reinterpret_cast<const float4*>(&sF[wave][l15][quad * 16 + k * 8 + 4]);
                const ushort4 f0 = *reinterpret_cast<const ushort4*>(fp + k * 8);
                const ushort4 f1 = *reinterpret_cast<const ushort4*>(fp + k * 8 + 4);
                o0.x = f2bf(v0.x + bf2f(f0.x)); o0.y = f2bf(v0.y + bf2f(f0.y));
                o0.z = f2bf(v0.z + bf2f(f0.z)); o0.w = f2bf(v0.w + bf2f(f0.w));
                o1.x = f2bf(v1.x + bf2f(f1.x)); o1.y = f2bf(v1.y + bf2f(f1.y));
                o1.z = f2bf(v1.z + bf2f(f1.z)); o1.w = f2bf(v1.w + bf2f(f1.w));
                *reinterpret_cast<ushort4*>(op + k * 8)     = o0;
                *reinterpret_cast<ushort4*>(op + k * 8 + 4) = o1;
            }
        } else {
            const float* fp = (const float*)feat + ob;
            float* op = (float*)out + ob;
            #pragma unroll
            for (int k = 0; k < 4; ++k) {
                float4 v = *reinterpret_cast<const float4*>(&sF[wave][l15][quad * 16 + k * 4]);
                float4 f = *reinterpret_cast<const float4*>(fp + k * 4);
                float4 o = {v.x + f.x, v.y + f.y, v.z + f.z, v.w + f.w};
                *reinterpret_cast<float4*>(op + k * 4) = o;
            }
        }
        COMPILER_FENCE();
    }
}

extern "C" void kernel_launch(void* const* d_in, const int* in_sizes, int n_in,
                              void* d_out, int out_size, void* d_ws, size_t ws_size,
                              hipStream_t stream) {
    const void* feat = d_in[0];
    const void* x    = d_in[1];
    const int* src   = (const int*)d_in[2];
    const int* dst   = (const int*)d_in[3];
    const void* W1   = d_in[4];
    const void* b1   = d_in[5];
    const void* W2   = d_in[6];
    const void* b2   = d_in[7];
    const void* we   = d_in[8];
    const void* be   = d_in[9];
    const void* U1   = d_in[10];
    const void* c1   = d_in[11];
    const void* U2   = d_in[12];
    const void* c2   = d_in[13];
    char* ws = (char*)d_ws;

    if (ws_size >= WS_NEED) {
        unsigned short* msg = (unsigned short*)(ws);
        int* deg  = (int*)(ws + DEG_OFF);
        int* offs = (int*)(ws + OFFS_OFF);
        int* pos  = (int*)(ws + POS_OFF);
        unsigned short* fb  = (unsigned short*)(ws + FB_OFF);
        unsigned short* w1t = (unsigned short*)(ws + W1T_OFF);
        unsigned short* w2t = (unsigned short*)(ws + W2T_OFF);
        unsigned short* u1t = (unsigned short*)(ws + U1T_OFF);
        unsigned short* u2t = (unsigned short*)(ws + U2T_OFF);

        hipMemsetAsync(deg, 0, 204800, stream);
        cvt_kernel<<<(N_NODES * HDIM / 8 + 255) / 256, 256, 0, stream>>>(feat, fb);
        prepw_kernel<<<80, 256, 0, stream>>>(feat, W1, W2, U1, U2, w1t, w2t, u1t, u2t);
        hist_kernel<<<1024, 256, 0, stream>>>(dst, deg);
        scan1_kernel<<<49, 1024, 0, stream>>>(deg, offs + 51200 - 64);
        scan2_kernel<<<1, 64, 0, stream>>>(offs + 51200 - 64, 49);
        scan3_kernel<<<49, 1024, 0, stream>>>(deg, offs + 51200 - 64, offs, pos);
        edge_kernel<true><<<2500, 256, 0, stream>>>(fb, w1t, w2t, feat, x, src, dst,
                                                    W1, b1, W2, b2, we, be,
                                                    nullptr, 0xFFFFFFFFu, msg, pos);
        node_kernel<true><<<((N_NODES + 15) / 16 + 3) / 4, 256, 0, stream>>>(
            msg, offs, nullptr, u1t, u2t, feat, U1, c1, U2, c2, d_out);
    } else {
        float* msum = (float*)ws;
        size_t need = (size_t)N_NODES * HDIM * sizeof(float);
        size_t clr  = need < ws_size ? need : ws_size;
        unsigned int cap = (unsigned int)(ws_size / sizeof(float));
        if (cap > (unsigned int)(N_NODES * HDIM)) cap = (unsigned int)(N_NODES * HDIM);

        hipMemsetAsync(msum, 0, clr, stream);
        edge_kernel<false><<<2500, 256, 0, stream>>>(nullptr, nullptr, nullptr, feat, x, src, dst,
                                                     W1, b1, W2, b2, we, be,
                                                     msum, cap, nullptr, nullptr);
        node_kernel<false><<<((N_NODES + 15) / 16 + 3) / 4, 256, 0, stream>>>(
            nullptr, nullptr, msum, nullptr, nullptr, feat, U1, c1, U2, c2, d_out);
    }
}

// Round 9
// 251.116 us; speedup vs baseline: 1.6330x; 1.1073x over previous
//
#include <hip/hip_runtime.h>
#include <hip/hip_bf16.h>
#include <stdint.h>

#define N_NODES 50000
#define N_EDGES 800000
#define HDIM 64
#define SCAN_N (N_NODES + 1)

// ---- workspace layout (CSR path) ----
#define MSG_BYTES  ((size_t)N_EDGES * HDIM * 2)      // 102,400,000 bf16 messages
#define INT_OFF    MSG_BYTES
#define DEG_OFF    (INT_OFF)
#define OFFS_OFF   (INT_OFF + 204800)
#define POS_OFF    (INT_OFF + 409600)
#define FB_OFF     (INT_OFF + 614400)
#define W1T_OFF    (FB_OFF + (size_t)N_NODES * HDIM * 2)
#define W2T_OFF    (W1T_OFF + 16384)
#define U1T_OFF    (W2T_OFF + 8192)
#define U2T_OFF    (U1T_OFF + 8192)
#define WS_NEED    (U2T_OFF + 8192)

// fused prep kernel block ranges
#define CVT_BLOCKS  1563              // ceil(3.2M/8/256)
#define PREPW_BLOCKS 80
#define HIST_BLOCKS 1024

typedef __attribute__((ext_vector_type(8))) short short8;
typedef __attribute__((ext_vector_type(4))) float floatx4;

__device__ __forceinline__ float bf2f(unsigned short u) {
    union { unsigned int i; float f; } v; v.i = ((unsigned int)u) << 16; return v.f;
}
__device__ __forceinline__ unsigned short f2bf(float f) {
    __hip_bfloat16 h = __float2bfloat16(f);
    return *reinterpret_cast<unsigned short*>(&h);
}

__device__ __forceinline__ int detect_is_bf16(const unsigned short* p) {
    int cnt = 0;
    #pragma unroll
    for (int i = 0; i < 64; ++i) {
        unsigned short b = p[i];
        int e = (b >> 7) & 0xFF;
        cnt += ((e >= 97 && e <= 157) || (b & 0x7FFF) == 0) ? 1 : 0;
    }
    return cnt >= 56;
}

__device__ __forceinline__ float getf(const void* p, unsigned int i, int isb) {
    return isb ? bf2f(((const unsigned short*)p)[i]) : ((const float*)p)[i];
}

__device__ __forceinline__ short8 get8bf(const void* p, unsigned int i, int isb) {
    if (isb) {
        return *reinterpret_cast<const short8*>((const short*)p + i);
    } else {
        const float4 f0 = *reinterpret_cast<const float4*>((const float*)p + i);
        const float4 f1 = *reinterpret_cast<const float4*>((const float*)p + i + 4);
        short8 a;
        a[0] = (short)f2bf(f0.x); a[1] = (short)f2bf(f0.y);
        a[2] = (short)f2bf(f0.z); a[3] = (short)f2bf(f0.w);
        a[4] = (short)f2bf(f1.x); a[5] = (short)f2bf(f1.y);
        a[6] = (short)f2bf(f1.z); a[7] = (short)f2bf(f1.w);
        return a;
    }
}

#define COMPILER_FENCE() asm volatile("" ::: "memory")
#define WAIT_LDS() __builtin_amdgcn_s_waitcnt(0xC07F)   // lgkmcnt(0) only

// ---------------------------------------------------------------------------
// Fused prep: feat->bf16 table | transposed bf16 weights | dst histogram.
// All three are independent; branch on blockIdx range.
// ---------------------------------------------------------------------------
__global__ __launch_bounds__(256) void prep_kernel(
    const void* __restrict__ feat, unsigned short* __restrict__ fb,
    const void* __restrict__ W1, const void* __restrict__ W2,
    const void* __restrict__ U1, const void* __restrict__ U2,
    unsigned short* __restrict__ w1t, unsigned short* __restrict__ w2t,
    unsigned short* __restrict__ u1t, unsigned short* __restrict__ u2t,
    const int* __restrict__ dst, int* __restrict__ deg)
{
    const int b = blockIdx.x;
    if (b < CVT_BLOCKS) {
        const int isb = detect_is_bf16((const unsigned short*)feat);
        int i = (b * 256 + threadIdx.x) * 8;
        if (i >= N_NODES * HDIM) return;
        if (isb) {
            *reinterpret_cast<uint4*>(fb + i) =
                *reinterpret_cast<const uint4*>((const unsigned short*)feat + i);
        } else {
            float4 f0 = *reinterpret_cast<const float4*>((const float*)feat + i);
            float4 f1 = *reinterpret_cast<const float4*>((const float*)feat + i + 4);
            ushort4 a = {f2bf(f0.x), f2bf(f0.y), f2bf(f0.z), f2bf(f0.w)};
            ushort4 c = {f2bf(f1.x), f2bf(f1.y), f2bf(f1.z), f2bf(f1.w)};
            *reinterpret_cast<ushort4*>(fb + i)     = a;
            *reinterpret_cast<ushort4*>(fb + i + 4) = c;
        }
    } else if (b < CVT_BLOCKS + PREPW_BLOCKS) {
        const int isb = detect_is_bf16((const unsigned short*)feat);
        int idx = (b - CVT_BLOCKS) * 256 + threadIdx.x;
        if (idx < 8192) {                               // W1T [64][128]
            int n = idx >> 7, k = idx & 127;
            w1t[idx] = f2bf(getf(W1, k * 64 + n, isb));
        } else if (idx < 12288) {                       // W2T [64][64]
            int i = idx - 8192, n = i >> 6, k = i & 63;
            w2t[i] = f2bf(getf(W2, k * 64 + n, isb));
        } else if (idx < 16384) {                       // U1T
            int i = idx - 12288, n = i >> 6, k = i & 63;
            u1t[i] = f2bf(getf(U1, k * 64 + n, isb));
        } else if (idx < 20480) {                       // U2T
            int i = idx - 16384, n = i >> 6, k = i & 63;
            u2t[i] = f2bf(getf(U2, k * 64 + n, isb));
        }
    } else {
        int e0 = (b - CVT_BLOCKS - PREPW_BLOCKS) * 256 + threadIdx.x;
        for (int e = e0; e < N_EDGES; e += HIST_BLOCKS * 256)
            atomicAdd(&deg[dst[e]], 1);
    }
}

// ---------------------------------------------------------------------------
// CSR scan (multi-block, r6-proven)
// ---------------------------------------------------------------------------
__global__ void scan1_kernel(const int* __restrict__ deg, int* __restrict__ part) {
    __shared__ int s[1024];
    int g = blockIdx.x * 1024 + threadIdx.x;
    s[threadIdx.x] = (g < SCAN_N) ? deg[g] : 0;
    __syncthreads();
    for (int off = 512; off > 0; off >>= 1) {
        if (threadIdx.x < off) s[threadIdx.x] += s[threadIdx.x + off];
        __syncthreads();
    }
    if (threadIdx.x == 0) part[blockIdx.x] = s[0];
}

__global__ void scan2_kernel(int* __restrict__ part, int nparts) {
    if (threadIdx.x == 0) {
        int run = 0;
        for (int i = 0; i < nparts; ++i) { int t = part[i]; part[i] = run; run += t; }
    }
}

__global__ void scan3_kernel(const int* __restrict__ deg, const int* __restrict__ part,
                             int* __restrict__ offs, int* __restrict__ pos) {
    __shared__ int s[1024];
    int g = blockIdx.x * 1024 + threadIdx.x;
    int v = (g < SCAN_N) ? deg[g] : 0;
    s[threadIdx.x] = v;
    __syncthreads();
    for (int off = 1; off < 1024; off <<= 1) {
        int t = (threadIdx.x >= off) ? s[threadIdx.x - off] : 0;
        __syncthreads();
        s[threadIdx.x] += t;
        __syncthreads();
    }
    int excl = s[threadIdx.x] - v + part[blockIdx.x];
    if (g < SCAN_N) { offs[g] = excl; pos[g] = excl; }
}

// ---------------------------------------------------------------------------
// Edge kernel: per wave, a 16-edge MFMA M-tile.
// CSR path: W1T/W2T fragments live in LDS (fragment-major, lane-contiguous
// 16B -> conflict-free ds_read_b128), freeing ~96 VGPRs/wave for occupancy.
// ---------------------------------------------------------------------------
template <bool CSR>
__global__ __launch_bounds__(256, 2) void edge_kernel(
    const unsigned short* __restrict__ fbf,
    const unsigned short* __restrict__ w1t, const unsigned short* __restrict__ w2t,
    const void* __restrict__ feat, const void* __restrict__ xpos,
    const int* __restrict__ src, const int* __restrict__ dst,
    const void* __restrict__ W1, const void* __restrict__ b1,
    const void* __restrict__ W2, const void* __restrict__ b2,
    const void* __restrict__ we, const void* __restrict__ be,
    float* __restrict__ msum, unsigned int msum_cap,
    unsigned short* __restrict__ msg, int* __restrict__ pos)
{
    __shared__ __align__(16) short sW1[16][64][8];   // frag f=c*4+nt, lane, 16B
    __shared__ __align__(16) short sW2[8][64][8];
    __shared__ __align__(16) short sA2[4][16][72];

    const int isb  = detect_is_bf16((const unsigned short*)feat);
    const int tid  = threadIdx.x;
    const int wave = tid >> 6;
    const int lane = tid & 63;
    const int l15  = lane & 15;
    const int quad = lane >> 4;

    short8 bw1[4][4];    // only used (and only initialized) in fallback path
    short8 bw2[2][4];
    if (CSR) {
        // stage transposed weights into fragment-major LDS (once per block)
        for (int i = tid; i < 16 * 64; i += 256) {
            int f = i >> 6, l = i & 63;
            int n = (f & 3) * 16 + (l & 15);
            int k0 = (f >> 2) * 32 + (l >> 4) * 8;
            *reinterpret_cast<short8*>(&sW1[f][l][0]) =
                *reinterpret_cast<const short8*>(w1t + n * 128 + k0);
        }
        for (int i = tid; i < 8 * 64; i += 256) {
            int f = i >> 6, l = i & 63;
            int n = (f & 3) * 16 + (l & 15);
            int k0 = (f >> 2) * 32 + (l >> 4) * 8;
            *reinterpret_cast<short8*>(&sW2[f][l][0]) =
                *reinterpret_cast<const short8*>(w2t + n * 64 + k0);
        }
        __syncthreads();
    } else {
        #pragma unroll
        for (int c = 0; c < 4; ++c)
            #pragma unroll
            for (int nt = 0; nt < 4; ++nt) {
                short8 b;
                #pragma unroll
                for (int j = 0; j < 8; ++j)
                    b[j] = (short)f2bf(getf(W1, (c * 32 + quad * 8 + j) * 64 + nt * 16 + l15, isb));
                bw1[c][nt] = b;
            }
        #pragma unroll
        for (int c = 0; c < 2; ++c)
            #pragma unroll
            for (int nt = 0; nt < 4; ++nt) {
                short8 b;
                #pragma unroll
                for (int j = 0; j < 8; ++j)
                    b[j] = (short)f2bf(getf(W2, (c * 32 + quad * 8 + j) * 64 + nt * 16 + l15, isb));
                bw2[c][nt] = b;
            }
    }

    float b1r[4], w1lr[4], b2r[4], wer[4];
    #pragma unroll
    for (int nt = 0; nt < 4; ++nt) {
        int n = nt * 16 + l15;
        b1r[nt]  = getf(b1, n, isb);
        w1lr[nt] = getf(W1, 128 * 64 + n, isb);
        b2r[nt]  = getf(b2, n, isb);
        wer[nt]  = getf(we, n, isb);
    }
    const float ber = getf(be, 0, isb);
    const int rowb = quad * 4;

    const int ntiles = N_EDGES / 64;
    for (int t = blockIdx.x; t < ntiles; t += gridDim.x) {
        const int ebase = t * 64 + wave * 16;

        int sidx = 0, didx = 0, slotv = 0;
        float sqd = 0.f;
        if (lane < 16) {
            int e = ebase + lane;
            sidx = src[e];
            didx = dst[e];
            if (CSR) slotv = atomicAdd(&pos[didx], 1);
            float dx = getf(xpos, sidx * 3 + 0, isb) - getf(xpos, didx * 3 + 0, isb);
            float dy = getf(xpos, sidx * 3 + 1, isb) - getf(xpos, didx * 3 + 1, isb);
            float dz = getf(xpos, sidx * 3 + 2, isb) - getf(xpos, didx * 3 + 2, isb);
            sqd = dx * dx + dy * dy + dz * dz;
        }
        const int sn     = __shfl(sidx, l15);
        const int dn_row = __shfl(didx, l15);

        // ---- layer 1: [16x128] @ [128x64] ----
        floatx4 acc[4];
        #pragma unroll
        for (int nt = 0; nt < 4; ++nt) acc[nt] = (floatx4){0.f, 0.f, 0.f, 0.f};
        #pragma unroll
        for (int c = 0; c < 4; ++c) {
            const int node = (c < 2) ? sn : dn_row;
            const unsigned int aoff = (unsigned int)node * 64u + (c & 1) * 32 + quad * 8;
            short8 a;
            if (CSR) a = *reinterpret_cast<const short8*>((const short*)fbf + aoff);
            else     a = get8bf(feat, aoff, isb);
            #pragma unroll
            for (int nt = 0; nt < 4; ++nt) {
                short8 b;
                if (CSR) b = *reinterpret_cast<const short8*>(&sW1[c * 4 + nt][lane][0]);
                else     b = bw1[c][nt];
                acc[nt] = __builtin_amdgcn_mfma_f32_16x16x32_bf16(a, b, acc[nt], 0, 0, 0);
            }
        }

        // ---- epilogue 1 -> LDS ----
        float sq[4];
        #pragma unroll
        for (int r = 0; r < 4; ++r) sq[r] = __shfl(sqd, rowb + r);
        #pragma unroll
        for (int nt = 0; nt < 4; ++nt)
            #pragma unroll
            for (int r = 0; r < 4; ++r) {
                float v = fmaxf(acc[nt][r] + b1r[nt] + sq[r] * w1lr[nt], 0.f);
                sA2[wave][rowb + r][nt * 16 + l15] = (short)f2bf(v);
            }
        COMPILER_FENCE();
        WAIT_LDS();

        // ---- layer 2: [16x64] @ [64x64] ----
        floatx4 acc2[4];
        #pragma unroll
        for (int nt = 0; nt < 4; ++nt) acc2[nt] = (floatx4){0.f, 0.f, 0.f, 0.f};
        #pragma unroll
        for (int c = 0; c < 2; ++c) {
            short8 a = *reinterpret_cast<const short8*>(&sA2[wave][l15][c * 32 + quad * 8]);
            #pragma unroll
            for (int nt = 0; nt < 4; ++nt) {
                short8 b;
                if (CSR) b = *reinterpret_cast<const short8*>(&sW2[c * 4 + nt][lane][0]);
                else     b = bw2[c][nt];
                acc2[nt] = __builtin_amdgcn_mfma_f32_16x16x32_bf16(a, b, acc2[nt], 0, 0, 0);
            }
        }
        COMPILER_FENCE();

        // ---- epilogue 2: relu, gate ----
        float mval[4][4];
        float part[4] = {0.f, 0.f, 0.f, 0.f};
        #pragma unroll
        for (int nt = 0; nt < 4; ++nt)
            #pragma unroll
            for (int r = 0; r < 4; ++r) {
                float v = fmaxf(acc2[nt][r] + b2r[nt], 0.f);
                mval[nt][r] = v;
                part[r] += v * wer[nt];
            }
        #pragma unroll
        for (int off = 1; off < 16; off <<= 1)
            #pragma unroll
            for (int r = 0; r < 4; ++r) part[r] += __shfl_xor(part[r], off);
        float gate[4];
        #pragma unroll
        for (int r = 0; r < 4; ++r)
            gate[r] = 1.f / (1.f + __expf(-(part[r] + ber)));

        if (CSR) {
            #pragma unroll
            for (int nt = 0; nt < 4; ++nt)
                #pragma unroll
                for (int r = 0; r < 4; ++r)
                    sA2[wave][rowb + r][nt * 16 + l15] = (short)f2bf(mval[nt][r] * gate[r]);
            COMPILER_FENCE();
            WAIT_LDS();
            int slot_r = __shfl(slotv, l15);
            const short8 v0 = *reinterpret_cast<const short8*>(&sA2[wave][l15][quad * 16]);
            const short8 v1 = *reinterpret_cast<const short8*>(&sA2[wave][l15][quad * 16 + 8]);
            unsigned short* mp = msg + (size_t)slot_r * 64 + quad * 16;
            *reinterpret_cast<short8*>(mp)     = v0;
            *reinterpret_cast<short8*>(mp + 8) = v1;
            COMPILER_FENCE();
        } else {
            #pragma unroll
            for (int r = 0; r < 4; ++r) {
                int dn = __shfl(didx, rowb + r);
                unsigned int base = (unsigned int)dn * 64u;
                if (base + 64u <= msum_cap) {
                    #pragma unroll
                    for (int nt = 0; nt < 4; ++nt)
                        unsafeAtomicAdd(&msum[base + nt * 16 + l15], mval[nt][r] * gate[r]);
                }
            }
        }
    }
}

// ---------------------------------------------------------------------------
// Node kernel: per wave a 16-node MFMA M-tile; fused msg reduction with
// 2-way ILP (even/odd row accumulators).
// ---------------------------------------------------------------------------
template <bool MSGRED>
__global__ __launch_bounds__(256, 2) void node_kernel(
    const unsigned short* __restrict__ msg, const int* __restrict__ offs,
    const float* __restrict__ msum,
    const unsigned short* __restrict__ u1t, const unsigned short* __restrict__ u2t,
    const void* __restrict__ feat,
    const void* __restrict__ U1, const void* __restrict__ c1v,
    const void* __restrict__ U2, const void* __restrict__ c2v,
    void* __restrict__ out)
{
    __shared__ __align__(16) short sT[4][16][72];
    __shared__ __align__(16) float sF[4][16][68];

    const int isb  = detect_is_bf16((const unsigned short*)feat);
    const int tid  = threadIdx.x;
    const int wave = tid >> 6;
    const int lane = tid & 63;
    const int l15  = lane & 15;
    const int quad = lane >> 4;

    short8 u1f[2][4], u2f[2][4];
    if (MSGRED) {
        #pragma unroll
        for (int nt = 0; nt < 4; ++nt) {
            const int n = nt * 16 + l15;
            #pragma unroll
            for (int c = 0; c < 2; ++c) {
                u1f[c][nt] = *reinterpret_cast<const short8*>(u1t + n * 64 + c * 32 + quad * 8);
                u2f[c][nt] = *reinterpret_cast<const short8*>(u2t + n * 64 + c * 32 + quad * 8);
            }
        }
    } else {
        #pragma unroll
        for (int c = 0; c < 2; ++c)
            #pragma unroll
            for (int nt = 0; nt < 4; ++nt) {
                short8 a, b;
                #pragma unroll
                for (int j = 0; j < 8; ++j) {
                    int k = c * 32 + quad * 8 + j, n = nt * 16 + l15;
                    a[j] = (short)f2bf(getf(U1, k * 64 + n, isb));
                    b[j] = (short)f2bf(getf(U2, k * 64 + n, isb));
                }
                u1f[c][nt] = a; u2f[c][nt] = b;
            }
    }
    float c1r[4], c2r[4];
    #pragma unroll
    for (int nt = 0; nt < 4; ++nt) {
        c1r[nt] = getf(c1v, nt * 16 + l15, isb);
        c2r[nt] = getf(c2v, nt * 16 + l15, isb);
    }
    const int rowb = quad * 4;

    const int ntile = (N_NODES + 15) / 16;   // 3125
    const int t = blockIdx.x * 4 + wave;
    if (t < ntile) {
        const int node = t * 16 + l15;

        // ---- message sum for this lane's 16 columns, 2-way ILP ----
        float acc16[16];
        #pragma unroll
        for (int i = 0; i < 16; ++i) acc16[i] = 0.f;
        if (MSGRED) {
            float accB[16];
            #pragma unroll
            for (int i = 0; i < 16; ++i) accB[i] = 0.f;
            int s = offs[node], e = offs[node + 1];
            int j = s;
            for (; j + 1 < e; j += 2) {
                const unsigned short* p0 = msg + (size_t)j * 64 + quad * 8;
                const unsigned short* p1 = msg + (size_t)(j + 1) * 64 + quad * 8;
                short8 a0 = *reinterpret_cast<const short8*>(p0);
                short8 a1 = *reinterpret_cast<const short8*>(p0 + 32);
                short8 b0 = *reinterpret_cast<const short8*>(p1);
                short8 b1 = *reinterpret_cast<const short8*>(p1 + 32);
                #pragma unroll
                for (int i = 0; i < 8; ++i) {
                    acc16[i]     += bf2f((unsigned short)a0[i]);
                    acc16[8 + i] += bf2f((unsigned short)a1[i]);
                    accB[i]      += bf2f((unsigned short)b0[i]);
                    accB[8 + i]  += bf2f((unsigned short)b1[i]);
                }
            }
            if (j < e) {
                const unsigned short* p0 = msg + (size_t)j * 64 + quad * 8;
                short8 a0 = *reinterpret_cast<const short8*>(p0);
                short8 a1 = *reinterpret_cast<const short8*>(p0 + 32);
                #pragma unroll
                for (int i = 0; i < 8; ++i) {
                    acc16[i]     += bf2f((unsigned short)a0[i]);
                    acc16[8 + i] += bf2f((unsigned short)a1[i]);
                }
            }
            #pragma unroll
            for (int i = 0; i < 16; ++i) acc16[i] += accB[i];
        } else {
            #pragma unroll
            for (int c = 0; c < 2; ++c) {
                unsigned int off = (unsigned int)node * 64u + c * 32 + quad * 8;
                float4 m0 = *reinterpret_cast<const float4*>(msum + off);
                float4 m1 = *reinterpret_cast<const float4*>(msum + off + 4);
                acc16[c * 8 + 0] = m0.x; acc16[c * 8 + 1] = m0.y;
                acc16[c * 8 + 2] = m0.z; acc16[c * 8 + 3] = m0.w;
                acc16[c * 8 + 4] = m1.x; acc16[c * 8 + 5] = m1.y;
                acc16[c * 8 + 6] = m1.z; acc16[c * 8 + 7] = m1.w;
            }
        }

        // ---- h fragments ----
        short8 ah[2];
        #pragma unroll
        for (int c = 0; c < 2; ++c) {
            unsigned int off = (unsigned int)node * 64u + c * 32 + quad * 8;
            float hv[8];
            if (isb) {
                short8 fv = *reinterpret_cast<const short8*>((const short*)feat + off);
                #pragma unroll
                for (int j = 0; j < 8; ++j) hv[j] = bf2f((unsigned short)fv[j]);
            } else {
                float4 f0 = *reinterpret_cast<const float4*>((const float*)feat + off);
                float4 f1 = *reinterpret_cast<const float4*>((const float*)feat + off + 4);
                hv[0] = f0.x; hv[1] = f0.y; hv[2] = f0.z; hv[3] = f0.w;
                hv[4] = f1.x; hv[5] = f1.y; hv[6] = f1.z; hv[7] = f1.w;
            }
            short8 a;
            #pragma unroll
            for (int j = 0; j < 8; ++j) a[j] = (short)f2bf(acc16[c * 8 + j] + hv[j]);
            ah[c] = a;
        }

        // ---- layer 1: relu(h@U1+c1) ----
        floatx4 acc[4];
        #pragma unroll
        for (int nt = 0; nt < 4; ++nt) acc[nt] = (floatx4){0.f, 0.f, 0.f, 0.f};
        #pragma unroll
        for (int c = 0; c < 2; ++c)
            #pragma unroll
            for (int nt = 0; nt < 4; ++nt)
                acc[nt] = __builtin_amdgcn_mfma_f32_16x16x32_bf16(ah[c], u1f[c][nt], acc[nt], 0, 0, 0);

        #pragma unroll
        for (int nt = 0; nt < 4; ++nt)
            #pragma unroll
            for (int r = 0; r < 4; ++r) {
                float v = fmaxf(acc[nt][r] + c1r[nt], 0.f);
                sT[wave][rowb + r][nt * 16 + l15] = (short)f2bf(v);
            }
        COMPILER_FENCE();
        WAIT_LDS();

        // ---- layer 2 ----
        floatx4 acc2[4];
        #pragma unroll
        for (int nt = 0; nt < 4; ++nt) acc2[nt] = (floatx4){0.f, 0.f, 0.f, 0.f};
        #pragma unroll
        for (int c = 0; c < 2; ++c) {
            short8 a = *reinterpret_cast<const short8*>(&sT[wave][l15][c * 32 + quad * 8]);
            #pragma unroll
            for (int nt = 0; nt < 4; ++nt)
                acc2[nt] = __builtin_amdgcn_mfma_f32_16x16x32_bf16(a, u2f[c][nt], acc2[nt], 0, 0, 0);
        }
        COMPILER_FENCE();

        // ---- epilogue: D-layout -> f32 LDS -> row-coalesced (+feat) store ----
        #pragma unroll
        for (int nt = 0; nt < 4; ++nt)
            #pragma unroll
            for (int r = 0; r < 4; ++r)
                sF[wave][rowb + r][nt * 16 + l15] = acc2[nt][r] + c2r[nt];
        COMPILER_FENCE();
        WAIT_LDS();

        const unsigned int ob = (unsigned int)node * 64u + quad * 16;
        if (isb) {
            const unsigned short* fp = (const unsigned short*)feat + ob;
            unsigned short* op = (unsigned short*)out + ob;
            #pragma unroll
            for (int k = 0; k < 2; ++k) {
                ushort4 o0, o1;
                float4 v0 = *reinterpret_cast<const float4*>(&sF[wave][l15][quad * 16 + k * 8]);
                float4 v1 = *reinterpret_cast<const float4*>(&sF[wave][l15][quad * 16 + k * 8 + 4]);
                const ushort4 f0 = *reinterpret_cast<const ushort4*>(fp + k * 8);
                const ushort4 f1 = *reinterpret_cast<const ushort4*>(fp + k * 8 + 4);
                o0.x = f2bf(v0.x + bf2f(f0.x)); o0.y = f2bf(v0.y + bf2f(f0.y));
                o0.z = f2bf(v0.z + bf2f(f0.z)); o0.w = f2bf(v0.w + bf2f(f0.w));
                o1.x = f2bf(v1.x + bf2f(f1.x)); o1.y = f2bf(v1.y + bf2f(f1.y));
                o1.z = f2bf(v1.z + bf2f(f1.z)); o1.w = f2bf(v1.w + bf2f(f1.w));
                *reinterpret_cast<ushort4*>(op + k * 8)     = o0;
                *reinterpret_cast<ushort4*>(op + k * 8 + 4) = o1;
            }
        } else {
            const float* fp = (const float*)feat + ob;
            float* op = (float*)out + ob;
            #pragma unroll
            for (int k = 0; k < 4; ++k) {
                float4 v = *reinterpret_cast<const float4*>(&sF[wave][l15][quad * 16 + k * 4]);
                float4 f = *reinterpret_cast<const float4*>(fp + k * 4);
                float4 o = {v.x + f.x, v.y + f.y, v.z + f.z, v.w + f.w};
                *reinterpret_cast<float4*>(op + k * 4) = o;
            }
        }
        COMPILER_FENCE();
    }
}

extern "C" void kernel_launch(void* const* d_in, const int* in_sizes, int n_in,
                              void* d_out, int out_size, void* d_ws, size_t ws_size,
                              hipStream_t stream) {
    const void* feat = d_in[0];
    const void* x    = d_in[1];
    const int* src   = (const int*)d_in[2];
    const int* dst   = (const int*)d_in[3];
    const void* W1   = d_in[4];
    const void* b1   = d_in[5];
    const void* W2   = d_in[6];
    const void* b2   = d_in[7];
    const void* we   = d_in[8];
    const void* be   = d_in[9];
    const void* U1   = d_in[10];
    const void* c1   = d_in[11];
    const void* U2   = d_in[12];
    const void* c2   = d_in[13];
    char* ws = (char*)d_ws;

    if (ws_size >= WS_NEED) {
        unsigned short* msg = (unsigned short*)(ws);
        int* deg  = (int*)(ws + DEG_OFF);
        int* offs = (int*)(ws + OFFS_OFF);
        int* pos  = (int*)(ws + POS_OFF);
        unsigned short* fb  = (unsigned short*)(ws + FB_OFF);
        unsigned short* w1t = (unsigned short*)(ws + W1T_OFF);
        unsigned short* w2t = (unsigned short*)(ws + W2T_OFF);
        unsigned short* u1t = (unsigned short*)(ws + U1T_OFF);
        unsigned short* u2t = (unsigned short*)(ws + U2T_OFF);

        hipMemsetAsync(deg, 0, 204800, stream);
        prep_kernel<<<CVT_BLOCKS + PREPW_BLOCKS + HIST_BLOCKS, 256, 0, stream>>>(
            feat, fb, W1, W2, U1, U2, w1t, w2t, u1t, u2t, dst, deg);
        scan1_kernel<<<49, 1024, 0, stream>>>(deg, offs + 51200 - 64);
        scan2_kernel<<<1, 64, 0, stream>>>(offs + 51200 - 64, 49);
        scan3_kernel<<<49, 1024, 0, stream>>>(deg, offs + 51200 - 64, offs, pos);
        edge_kernel<true><<<2500, 256, 0, stream>>>(fb, w1t, w2t, feat, x, src, dst,
                                                    W1, b1, W2, b2, we, be,
                                                    nullptr, 0xFFFFFFFFu, msg, pos);
        node_kernel<true><<<((N_NODES + 15) / 16 + 3) / 4, 256, 0, stream>>>(
            msg, offs, nullptr, u1t, u2t, feat, U1, c1, U2, c2, d_out);
    } else {
        float* msum = (float*)ws;
        size_t need = (size_t)N_NODES * HDIM * sizeof(float);
        size_t clr  = need < ws_size ? need : ws_size;
        unsigned int cap = (unsigned int)(ws_size / sizeof(float));
        if (cap > (unsigned int)(N_NODES * HDIM)) cap = (unsigned int)(N_NODES * HDIM);

        hipMemsetAsync(msum, 0, clr, stream);
        edge_kernel<false><<<2500, 256, 0, stream>>>(nullptr, nullptr, nullptr, feat, x, src, dst,
                                                     W1, b1, W2, b2, we, be,
                                                     msum, cap, nullptr, nullptr);
        node_kernel<false><<<((N_NODES + 15) / 16 + 3) / 4, 256, 0, stream>>>(
            nullptr, nullptr, msum, nullptr, nullptr, feat, U1, c1, U2, c2, d_out);
    }
}